// Round 9
// baseline (442.302 us; speedup 1.0000x reference)
//
#include <hip/hip_runtime.h>

typedef unsigned short u16;
typedef __attribute__((ext_vector_type(8))) short short8;
typedef __attribute__((ext_vector_type(4))) float fx4;
typedef __attribute__((ext_vector_type(4))) int ix4;
typedef __attribute__((ext_vector_type(4))) unsigned short ux4;
typedef __attribute__((ext_vector_type(4))) unsigned int uix4;

__device__ __forceinline__ float bf2f(u16 h) {
  union { unsigned u; float f; } a; a.u = ((unsigned)h) << 16; return a.f;
}
__device__ __forceinline__ u16 f2bf(float f) {
  union { float f; unsigned u; } a; a.f = f;
  unsigned u = a.u;
  return (u16)((u + 0x7FFFu + ((u >> 16) & 1u)) >> 16);  // RNE
}
__device__ __forceinline__ unsigned pk2bf(float lo, float hi) {
  return (unsigned)f2bf(lo) | ((unsigned)f2bf(hi) << 16);
}

// async global->LDS, 16B per lane. LDS dest must be wave-uniform base + lane*16.
__device__ __forceinline__ void gl_lds(const u16* g, u16* l) {
  __builtin_amdgcn_global_load_lds(
      (const __attribute__((address_space(1))) unsigned*)g,
      (__attribute__((address_space(3))) unsigned*)l, 16, 0, 0);
}

constexpr int S_LEN = 2048;
constexpr int DM = 2048;
constexpr int HD = 128;
constexpr int NH = 16;
constexpr float NEG = -1.0e9f;
constexpr float SC2 = 0.08838834764831845f * 1.4426950408889634f;  // 1/sqrt(128)*log2(e)
constexpr float INV2PI = 0.15915494309189535f;

// HW sin/cos: v_sin/v_cos take revolutions; pre-reduce with fract.
// (R5-R8: absmax unchanged -> verified.)
__device__ __forceinline__ void fast_sincos(float rev_unred, float& sn, float& cs) {
  float rev = rev_unred - floorf(rev_unred);
  sn = __builtin_amdgcn_sinf(rev);
  cs = __builtin_amdgcn_cosf(rev);
}

// ---------------------------------------------------------------------------
// fp32 -> bf16 bulk convert, all three tensors in ONE launch (x, Wqkv, Wout).
// ---------------------------------------------------------------------------
__global__ __launch_bounds__(256)
void cvt3_kernel(const float* __restrict__ x, const float* __restrict__ wq,
                 const float* __restrict__ wo,
                 u16* __restrict__ xb, u16* __restrict__ wqb, u16* __restrict__ wob)
{
  int bid = blockIdx.x;
  const float* in; u16* out; int base;
  if (bid < 8192)       { in = x;  out = xb;  base = bid; }
  else if (bid < 20480) { in = wq; out = wqb; base = bid - 8192; }
  else                  { in = wo; out = wob; base = bid - 20480; }
  size_t idx = (size_t)base * 256 + threadIdx.x;
  fx4 v = *(const fx4*)&in[idx * 4];
  ux4 pk;
  pk[0] = f2bf(v[0]); pk[1] = f2bf(v[1]); pk[2] = f2bf(v[2]); pk[3] = f2bf(v[3]);
  *(ux4*)&out[idx * 4] = pk;
}

// ---------------------------------------------------------------------------
// GEMM: C[M,N] = A[M,K] @ W[N,K]^T + bias (bias fp32)
// MODE 0: fp32 out to o0;  MODE 1: QKV scatter bf16 (o0=Q, o1=K, o2=V^T)
//         with RoPE fused into the Q/K epilogue (HW v_sin/v_cos).
// 2D grid (n fastest): concurrent blocks share one A-panel + few W-panels in
// each XCD L2 -- measured best (R6's XCD column-ownership DOUBLED fetch).
// Keep the proven 2-barrier loop; phased rewrites regressed twice.
// ---------------------------------------------------------------------------
template<int M, int N, int K, int MODE, bool AB16, bool WB16>
__global__ __launch_bounds__(256)
void gemm_bt(const void* __restrict__ Av, const void* __restrict__ Wv,
             const float* __restrict__ bias,
             void* __restrict__ o0, u16* __restrict__ o1, u16* __restrict__ o2)
{
  constexpr int BK = 64;
  __shared__ u16 la[128 * BK];
  __shared__ u16 lb[128 * BK];
  const int tid  = threadIdx.x;
  const int lane = tid & 63;
  const int wv   = tid >> 6;
  const int wm   = wv >> 1, wn = wv & 1;
  const int quad = lane >> 4, l16 = lane & 15;
  const int m0 = blockIdx.y * 128, n0 = blockIdx.x * 128;
  const int sw = l16 & 7;                     // frag-read swizzle (row&7 = l16&7)

  fx4 acc[4][4] = {};

  for (int k0 = 0; k0 < K; k0 += BK) {
    __syncthreads();
    if constexpr (AB16) {
      const u16* ap = (const u16*)Av + (size_t)m0 * K + k0;
      #pragma unroll
      for (int i = 0; i < 4; ++i) {
        int c = i * 256 + tid, row = c >> 3, cc = c & 7;
        int g = cc ^ (row & 7);
        gl_lds(ap + (size_t)row * K + g * 8, &la[c * 8]);
      }
    } else {
      const float* ap = (const float*)Av + (size_t)m0 * K + k0;
      #pragma unroll
      for (int i = 0; i < 4; ++i) {
        int c = i * 256 + tid, row = c >> 3, cc = c & 7;
        fx4 v0 = *(const fx4*)&ap[(size_t)row * K + cc * 8];
        fx4 v1 = *(const fx4*)&ap[(size_t)row * K + cc * 8 + 4];
        ux4 p0, p1;
        p0[0]=f2bf(v0[0]); p0[1]=f2bf(v0[1]); p0[2]=f2bf(v0[2]); p0[3]=f2bf(v0[3]);
        p1[0]=f2bf(v1[0]); p1[1]=f2bf(v1[1]); p1[2]=f2bf(v1[2]); p1[3]=f2bf(v1[3]);
        int s = cc ^ (row & 7);
        *(ux4*)&la[row * BK + s * 8]     = p0;
        *(ux4*)&la[row * BK + s * 8 + 4] = p1;
      }
    }
    if constexpr (WB16) {
      const u16* wp = (const u16*)Wv + (size_t)n0 * K + k0;
      #pragma unroll
      for (int i = 0; i < 4; ++i) {
        int c = i * 256 + tid, row = c >> 3, cc = c & 7;
        int g = cc ^ (row & 7);
        gl_lds(wp + (size_t)row * K + g * 8, &lb[c * 8]);
      }
    } else {
      const float* wp = (const float*)Wv + (size_t)n0 * K + k0;
      #pragma unroll
      for (int i = 0; i < 4; ++i) {
        int c = i * 256 + tid, row = c >> 3, cc = c & 7;
        fx4 v0 = *(const fx4*)&wp[(size_t)row * K + cc * 8];
        fx4 v1 = *(const fx4*)&wp[(size_t)row * K + cc * 8 + 4];
        ux4 p0, p1;
        p0[0]=f2bf(v0[0]); p0[1]=f2bf(v0[1]); p0[2]=f2bf(v0[2]); p0[3]=f2bf(v0[3]);
        p1[0]=f2bf(v1[0]); p1[1]=f2bf(v1[1]); p1[2]=f2bf(v1[2]); p1[3]=f2bf(v1[3]);
        int s = cc ^ (row & 7);
        *(ux4*)&lb[row * BK + s * 8]     = p0;
        *(ux4*)&lb[row * BK + s * 8 + 4] = p1;
      }
    }
    __syncthreads();
    #pragma unroll
    for (int ks = 0; ks < 2; ++ks) {
      short8 af[4], bfg[4];
      #pragma unroll
      for (int t = 0; t < 4; ++t) {
        int arow = wm * 64 + t * 16 + l16;
        int brow = (t & 2) * 32 + wn * 32 + (t & 1) * 16 + l16;
        int cc = (ks * 4 + quad) ^ sw;
        af[t]  = *(const short8*)&la[arow * BK + cc * 8];
        bfg[t] = *(const short8*)&lb[brow * BK + cc * 8];
      }
      #pragma unroll
      for (int mt = 0; mt < 4; ++mt)
        #pragma unroll
        for (int nt = 0; nt < 4; ++nt)
          acc[mt][nt] = __builtin_amdgcn_mfma_f32_16x16x32_bf16(af[mt], bfg[nt], acc[mt][nt], 0, 0, 0);
    }
  }

  if constexpr (MODE == 0) {
    float* of = (float*)o0;
    #pragma unroll
    for (int nt = 0; nt < 4; ++nt) {
      int col = n0 + (nt & 2) * 32 + wn * 32 + (nt & 1) * 16 + l16;
      float bz = bias[col];
      #pragma unroll
      for (int mt = 0; mt < 4; ++mt) {
        int row = m0 + wm * 64 + mt * 16 + quad * 4;
        #pragma unroll
        for (int r = 0; r < 4; ++r)
          of[(size_t)(row + r) * N + col] = acc[mt][nt][r] + bz;
      }
    }
  } else {
    const int which = n0 >> 11;
    const int head  = (n0 >> 7) & 15;
    const int b     = m0 >> 11;
    const int bh    = b * NH + head;
    if (which == 2) {
      #pragma unroll
      for (int nt = 0; nt < 4; ++nt) {
        int dcol = (nt & 2) * 32 + wn * 32 + (nt & 1) * 16 + l16;
        float bz = bias[n0 + dcol];
        #pragma unroll
        for (int mt = 0; mt < 4; ++mt) {
          int srow = (m0 & (S_LEN - 1)) + wm * 64 + mt * 16 + quad * 4;
          ux4 pk;
          #pragma unroll
          for (int r = 0; r < 4; ++r) pk[r] = f2bf(acc[mt][nt][r] + bz);
          *(ux4*)&o2[((size_t)bh * HD + dcol) * S_LEN + srow] = pk;  // V^T
        }
      }
    } else {
      // Q or K with fused RoPE: pair (i, i+64) = acc[..][nt] / acc[..][nt+2]
      u16* buf = (which == 0) ? (u16*)o0 : o1;
      #pragma unroll
      for (int nt = 0; nt < 2; ++nt) {
        int i = wn * 32 + nt * 16 + l16;            // 0..63
        // invf2 = 10000^(-i/64) / (2*pi): angle in revolutions per srow
        float invf2 = exp2f((float)i * -0.20762050594f) * INV2PI;
        float bz1 = bias[n0 + i];
        float bz2 = bias[n0 + i + 64];
        #pragma unroll
        for (int mt = 0; mt < 4; ++mt) {
          int srow = (m0 & (S_LEN - 1)) + wm * 64 + mt * 16 + quad * 4;
          size_t base = ((size_t)bh * S_LEN + srow) * HD + i;
          #pragma unroll
          for (int r = 0; r < 4; ++r) {
            float sn, cs;
            fast_sincos((float)(srow + r) * invf2, sn, cs);
            float v1 = acc[mt][nt][r] + bz1;
            float v2 = acc[mt][nt + 2][r] + bz2;
            buf[base + (size_t)r * HD]      = f2bf(v1 * cs - v2 * sn);
            buf[base + (size_t)r * HD + 64] = f2bf(v2 * cs + v1 * sn);
          }
        }
      }
    }
  }
}

// ---------------------------------------------------------------------------
// Transposed online-softmax tile step with defer-max (T13), P IN REGISTERS:
// outputs pw[snt][t] = bf16-pair pack of P[q][snt*16+quad*4+{2t,2t+1}].
// No LDS traffic; PV rebuilds the B-frag via 16 shfl + selects (see below).
// ---------------------------------------------------------------------------
__device__ __forceinline__ void soft_tile_reg(fx4 s[4], float& m, float& l, fx4* o,
                                              unsigned pw[4][2], bool mask,
                                              int qrow, int k0, int l16, int quad)
{
  #pragma unroll
  for (int snt = 0; snt < 4; ++snt)
    #pragma unroll
    for (int r = 0; r < 4; ++r) {
      float v = s[snt][r] * SC2;
      if (mask && (k0 + snt * 16 + quad * 4 + r > qrow)) v = NEG;
      s[snt][r] = v;
    }
  float mx = s[0][0];
  #pragma unroll
  for (int snt = 0; snt < 4; ++snt)
    #pragma unroll
    for (int r = 0; r < 4; ++r) mx = fmaxf(mx, s[snt][r]);
  mx = fmaxf(mx, __shfl_xor(mx, 16, 64));
  mx = fmaxf(mx, __shfl_xor(mx, 32, 64));

  const bool defer = __all(mx <= m + 8.f);   // wave-uniform
  float al = 1.f;
  if (!defer) {
    float mn = fmaxf(m, mx);
    al = exp2f(m - mn);
    m = mn;
  }
  float rs = 0.f;
  #pragma unroll
  for (int snt = 0; snt < 4; ++snt)
    #pragma unroll
    for (int r = 0; r < 4; ++r) {
      float pz = exp2f(s[snt][r] - m);
      s[snt][r] = pz;
      rs += pz;
    }
  rs += __shfl_xor(rs, 16, 64);
  rs += __shfl_xor(rs, 32, 64);
  l = l * al + rs;
  if (!defer) {
    #pragma unroll
    for (int nd = 0; nd < 8; ++nd)
      #pragma unroll
      for (int r = 0; r < 4; ++r) o[nd][r] *= al;
  }
  #pragma unroll
  for (int snt = 0; snt < 4; ++snt) {
    pw[snt][0] = pk2bf(s[snt][0], s[snt][1]);
    pw[snt][1] = pk2bf(s[snt][2], s[snt][3]);
  }
}

// ---------------------------------------------------------------------------
// Flash attention (causal), UNPAIRED q-tiles, XCD-grouped bh, ascending qt,
// defer-max, setprio -- R8-proven config, now with P IN REGISTERS:
// LDS = lk + lv only = 32768 B, launch_bounds(256,4) -> 4 blocks/CU
// (16 waves, +33% TLP over R8's 3 blocks; TLP is the proven lever here).
//
// PV B-frag reconstruction (index-verified): lane (q=l16, quad) needs
// P[q][kk*32 + quad*8 + j], j=0..7 as 4 bf16-pair words. Word w comes from
// source lane s0=(quad&1)*32+l16 (w=0,1) or s0+16 (w=2,3), register
// pw[2kk + (quad>>1)][w&1]. snt index is lane-dependent -> pull BOTH snt
// candidates and cndmask-select (static register indexing, rule #20 safe).
// ---------------------------------------------------------------------------
__global__ __launch_bounds__(256, 4)
void attn_kernel(const u16* __restrict__ qbuf, const u16* __restrict__ kbuf,
                 const u16* __restrict__ vtbuf, u16* __restrict__ ctx)
{
  __shared__ u16 lk[64 * 128];     // K tile  [key][d],  swizzled chunks (16 KiB)
  __shared__ u16 lv[128 * 64];     // V^T tile [d][key], swizzled chunks (16 KiB)
  const int tid = threadIdx.x, lane = tid & 63;
  const int quad = lane >> 4, l16 = lane & 15;
  const int w = blockIdx.x;
  const int bh = (w & 7) * 4 + ((w >> 3) >> 5);   // XCD-grouped head
  const int qt = (w >> 3) & 31;                   // q-tile 0..31 (ascending)
  const int head = bh & 15, b = bh >> 4;
  const int s8 = l16 & 7;          // frag-read swizzle index
  const int wvq = (tid >> 6);      // wave id (q-row group)

  short8 qh[4];
  {
    const size_t q_ = ((size_t)bh * S_LEN + qt * 64 + wvq * 16 + l16) * HD;
    #pragma unroll
    for (int kd = 0; kd < 4; ++kd)
      qh[kd] = *(const short8*)&qbuf[q_ + kd * 32 + quad * 8];
  }

  fx4 oh[8] = {};
  float m = NEG, l = 0.f;
  const int qrow = qt * 64 + wvq * 16 + l16;
  const int sl0 = (quad & 1) * 32 + l16;    // shuffle source lanes
  const int sl1 = sl0 + 16;
  const bool hiq = quad >= 2;

  for (int kt = 0; kt <= qt; ++kt) {
    if (kt) __syncthreads();                 // WAR vs previous compute
    {
      const u16* kg = kbuf + ((size_t)bh * S_LEN + kt * 64) * HD;
      const u16* vg = vtbuf + (size_t)bh * HD * S_LEN + kt * 64;
      #pragma unroll
      for (int i = 0; i < 4; ++i) {          // K tile: 64 rows x 16 chunks
        int c = i * 256 + tid;
        int row = c >> 4, cc = c & 15;
        int g = cc ^ (row & 7);
        gl_lds(kg + (size_t)row * HD + g * 8, &lk[c * 8]);
      }
      #pragma unroll
      for (int i = 0; i < 4; ++i) {          // V^T tile: 128 rows x 8 chunks
        int c = i * 256 + tid;
        int row = c >> 3, cc = c & 7;
        int g = cc ^ (row & 7);
        gl_lds(vg + (size_t)row * S_LEN + g * 8, &lv[c * 8]);
      }
    }
    __syncthreads();                         // RAW: drain stage

    // S^T = K·Q^T
    fx4 sh[4] = {};
    __builtin_amdgcn_s_setprio(1);
    #pragma unroll
    for (int snt = 0; snt < 4; ++snt) {
      #pragma unroll
      for (int kd = 0; kd < 4; ++kd) {
        int cc = (kd * 4 + quad) ^ s8;
        short8 kf = *(const short8*)&lk[(snt * 16 + l16) * 128 + cc * 8];
        sh[snt] = __builtin_amdgcn_mfma_f32_16x16x32_bf16(kf, qh[kd], sh[snt], 0, 0, 0);
      }
    }
    __builtin_amdgcn_s_setprio(0);

    unsigned pw[4][2];
    soft_tile_reg(sh, m, l, oh, pw, kt == qt, qrow, kt * 64, l16, quad);

    // O^T += V^T·P^T; P B-frag via shuffles (no LDS)
    __builtin_amdgcn_s_setprio(1);
    #pragma unroll
    for (int kk = 0; kk < 2; ++kk) {
      unsigned a0 = __shfl((int)pw[2 * kk][0],     sl0, 64);
      unsigned b0 = __shfl((int)pw[2 * kk + 1][0], sl0, 64);
      unsigned a1 = __shfl((int)pw[2 * kk][1],     sl0, 64);
      unsigned b1 = __shfl((int)pw[2 * kk + 1][1], sl0, 64);
      unsigned c0 = __shfl((int)pw[2 * kk][0],     sl1, 64);
      unsigned d0 = __shfl((int)pw[2 * kk + 1][0], sl1, 64);
      unsigned c1 = __shfl((int)pw[2 * kk][1],     sl1, 64);
      unsigned d1 = __shfl((int)pw[2 * kk + 1][1], sl1, 64);
      uix4 wv_;
      wv_[0] = hiq ? b0 : a0;
      wv_[1] = hiq ? b1 : a1;
      wv_[2] = hiq ? d0 : c0;
      wv_[3] = hiq ? d1 : c1;
      short8 ph = __builtin_bit_cast(short8, wv_);
      #pragma unroll
      for (int nd = 0; nd < 8; ++nd) {
        int cc = (kk * 4 + quad) ^ s8;
        short8 vf = *(const short8*)&lv[(nd * 16 + l16) * 64 + cc * 8];
        oh[nd] = __builtin_amdgcn_mfma_f32_16x16x32_bf16(vf, ph, oh[nd], 0, 0, 0);
      }
    }
    __builtin_amdgcn_s_setprio(0);
  }

  // O^T regs: lane q=l16, d = nd*16 + quad*4 + r  -> 8B packed stores
  {
    float ih = 1.f / l;
    size_t rh = ((size_t)b * S_LEN + qt * 64 + wvq * 16 + l16) * DM + head * HD;
    #pragma unroll
    for (int nd = 0; nd < 8; ++nd) {
      ux4 ph;
      #pragma unroll
      for (int r = 0; r < 4; ++r) ph[r] = f2bf(oh[nd][r] * ih);
      *(ux4*)&ctx[rh + nd * 16 + quad * 4] = ph;
    }
  }
}

// ---------------------------------------------------------------------------
extern "C" void kernel_launch(void* const* d_in, const int* in_sizes, int n_in,
                              void* d_out, int out_size, void* d_ws, size_t ws_size,
                              hipStream_t stream)
{
  const float* x    = (const float*)d_in[0];
  const float* Wqkv = (const float*)d_in[2];
  const float* bqkv = (const float*)d_in[3];
  const float* Wout = (const float*)d_in[4];
  const float* bout = (const float*)d_in[5];
  float* out = (float*)d_out;

  constexpr size_t XB_E = (size_t)4096 * 2048;   // 8.39M elems
  constexpr size_t WQ_E = (size_t)6144 * 2048;
  constexpr size_t WO_E = (size_t)2048 * 2048;
  constexpr size_t NEED = (XB_E + WQ_E + WO_E + 3 * XB_E) * 2;  // ~101 MB

  if (ws_size >= NEED) {
    u16* xb  = (u16*)d_ws;
    u16* wqb = xb + XB_E;
    u16* wob = wqb + WQ_E;
    u16* qb  = wob + WO_E;
    u16* kb  = qb + XB_E;
    u16* vb  = kb + XB_E;
    u16* ctx = xb;                 // xb dead after QKV GEMM; reuse for ctx

    cvt3_kernel<<<dim3(24576), 256, 0, stream>>>(x, Wqkv, Wout, xb, wqb, wob);
    gemm_bt<4096, 6144, 2048, 1, true, true><<<dim3(48, 32), 256, 0, stream>>>(
        xb, wqb, bqkv, qb, kb, vb);
    attn_kernel<<<dim3(1024), 256, 0, stream>>>(qb, kb, vb, ctx);
    gemm_bt<4096, 2048, 2048, 0, true, true><<<dim3(16, 32), 256, 0, stream>>>(
        ctx, wob, bout, out, nullptr, nullptr);
  } else {
    // fallback: 48 MiB ws, fused fp32->bf16 staging in GEMMs, ctx in d_out
    u16* qb = (u16*)d_ws;
    u16* kb = qb + XB_E;
    u16* vb = kb + XB_E;
    u16* ctx = (u16*)d_out;
    float* tmpo = (float*)d_ws;   // over dead qb/kb at out-proj time

    gemm_bt<4096, 6144, 2048, 1, false, false><<<dim3(48, 32), 256, 0, stream>>>(
        x, Wqkv, bqkv, qb, kb, vb);
    attn_kernel<<<dim3(1024), 256, 0, stream>>>(qb, kb, vb, ctx);
    gemm_bt<4096, 2048, 2048, 0, true, false><<<dim3(16, 32), 256, 0, stream>>>(
        ctx, Wout, bout, tmpo, nullptr, nullptr);
    hipMemcpyAsync(out, tmpo, (size_t)out_size * sizeof(float),
                   hipMemcpyDeviceToDevice, stream);
  }
}

// Round 10
// 410.157 us; speedup vs baseline: 1.0784x; 1.0784x over previous
//
#include <hip/hip_runtime.h>

typedef unsigned short u16;
typedef __attribute__((ext_vector_type(8))) short short8;
typedef __attribute__((ext_vector_type(4))) float fx4;
typedef __attribute__((ext_vector_type(4))) int ix4;
typedef __attribute__((ext_vector_type(4))) unsigned short ux4;

__device__ __forceinline__ float bf2f(u16 h) {
  union { unsigned u; float f; } a; a.u = ((unsigned)h) << 16; return a.f;
}
__device__ __forceinline__ u16 f2bf(float f) {
  union { float f; unsigned u; } a; a.f = f;
  unsigned u = a.u;
  return (u16)((u + 0x7FFFu + ((u >> 16) & 1u)) >> 16);  // RNE
}

// async global->LDS, 16B per lane. LDS dest must be wave-uniform base + lane*16.
__device__ __forceinline__ void gl_lds(const u16* g, u16* l) {
  __builtin_amdgcn_global_load_lds(
      (const __attribute__((address_space(1))) unsigned*)g,
      (__attribute__((address_space(3))) unsigned*)l, 16, 0, 0);
}

constexpr int S_LEN = 2048;
constexpr int DM = 2048;
constexpr int HD = 128;
constexpr int NH = 16;
constexpr float NEG = -1.0e9f;
constexpr float SC2 = 0.08838834764831845f * 1.4426950408889634f;  // 1/sqrt(128)*log2(e)
constexpr float INV2PI = 0.15915494309189535f;

// HW sin/cos: v_sin/v_cos take revolutions; pre-reduce with fract.
// (R5-R9: absmax unchanged -> verified.)
__device__ __forceinline__ void fast_sincos(float rev_unred, float& sn, float& cs) {
  float rev = rev_unred - floorf(rev_unred);
  sn = __builtin_amdgcn_sinf(rev);
  cs = __builtin_amdgcn_cosf(rev);
}

// ---------------------------------------------------------------------------
// fp32 -> bf16 bulk convert, all three tensors in ONE launch (x, Wqkv, Wout).
// ---------------------------------------------------------------------------
__global__ __launch_bounds__(256)
void cvt3_kernel(const float* __restrict__ x, const float* __restrict__ wq,
                 const float* __restrict__ wo,
                 u16* __restrict__ xb, u16* __restrict__ wqb, u16* __restrict__ wob)
{
  int bid = blockIdx.x;
  const float* in; u16* out; int base;
  if (bid < 8192)       { in = x;  out = xb;  base = bid; }
  else if (bid < 20480) { in = wq; out = wqb; base = bid - 8192; }
  else                  { in = wo; out = wob; base = bid - 20480; }
  size_t idx = (size_t)base * 256 + threadIdx.x;
  fx4 v = *(const fx4*)&in[idx * 4];
  ux4 pk;
  pk[0] = f2bf(v[0]); pk[1] = f2bf(v[1]); pk[2] = f2bf(v[2]); pk[3] = f2bf(v[3]);
  *(ux4*)&out[idx * 4] = pk;
}

// ---------------------------------------------------------------------------
// GEMM: C[M,N] = A[M,K] @ W[N,K]^T + bias (bias fp32)
// MODE 0: fp32 out to o0;  MODE 1: QKV scatter bf16 (o0=Q, o1=K, o2=V^T)
//         with RoPE fused into the Q/K epilogue (HW v_sin/v_cos).
// 2D grid (n fastest): concurrent blocks share one A-panel + few W-panels in
// each XCD L2 -- measured best (R6's XCD column-ownership DOUBLED fetch).
// Keep the proven 2-barrier loop; phased rewrites regressed twice.
// ---------------------------------------------------------------------------
template<int M, int N, int K, int MODE, bool AB16, bool WB16>
__global__ __launch_bounds__(256)
void gemm_bt(const void* __restrict__ Av, const void* __restrict__ Wv,
             const float* __restrict__ bias,
             void* __restrict__ o0, u16* __restrict__ o1, u16* __restrict__ o2)
{
  constexpr int BK = 64;
  __shared__ u16 la[128 * BK];
  __shared__ u16 lb[128 * BK];
  const int tid  = threadIdx.x;
  const int lane = tid & 63;
  const int wv   = tid >> 6;
  const int wm   = wv >> 1, wn = wv & 1;
  const int quad = lane >> 4, l16 = lane & 15;
  const int m0 = blockIdx.y * 128, n0 = blockIdx.x * 128;
  const int sw = l16 & 7;                     // frag-read swizzle (row&7 = l16&7)

  fx4 acc[4][4] = {};

  for (int k0 = 0; k0 < K; k0 += BK) {
    __syncthreads();
    if constexpr (AB16) {
      const u16* ap = (const u16*)Av + (size_t)m0 * K + k0;
      #pragma unroll
      for (int i = 0; i < 4; ++i) {
        int c = i * 256 + tid, row = c >> 3, cc = c & 7;
        int g = cc ^ (row & 7);
        gl_lds(ap + (size_t)row * K + g * 8, &la[c * 8]);
      }
    } else {
      const float* ap = (const float*)Av + (size_t)m0 * K + k0;
      #pragma unroll
      for (int i = 0; i < 4; ++i) {
        int c = i * 256 + tid, row = c >> 3, cc = c & 7;
        fx4 v0 = *(const fx4*)&ap[(size_t)row * K + cc * 8];
        fx4 v1 = *(const fx4*)&ap[(size_t)row * K + cc * 8 + 4];
        ux4 p0, p1;
        p0[0]=f2bf(v0[0]); p0[1]=f2bf(v0[1]); p0[2]=f2bf(v0[2]); p0[3]=f2bf(v0[3]);
        p1[0]=f2bf(v1[0]); p1[1]=f2bf(v1[1]); p1[2]=f2bf(v1[2]); p1[3]=f2bf(v1[3]);
        int s = cc ^ (row & 7);
        *(ux4*)&la[row * BK + s * 8]     = p0;
        *(ux4*)&la[row * BK + s * 8 + 4] = p1;
      }
    }
    if constexpr (WB16) {
      const u16* wp = (const u16*)Wv + (size_t)n0 * K + k0;
      #pragma unroll
      for (int i = 0; i < 4; ++i) {
        int c = i * 256 + tid, row = c >> 3, cc = c & 7;
        int g = cc ^ (row & 7);
        gl_lds(wp + (size_t)row * K + g * 8, &lb[c * 8]);
      }
    } else {
      const float* wp = (const float*)Wv + (size_t)n0 * K + k0;
      #pragma unroll
      for (int i = 0; i < 4; ++i) {
        int c = i * 256 + tid, row = c >> 3, cc = c & 7;
        fx4 v0 = *(const fx4*)&wp[(size_t)row * K + cc * 8];
        fx4 v1 = *(const fx4*)&wp[(size_t)row * K + cc * 8 + 4];
        ux4 p0, p1;
        p0[0]=f2bf(v0[0]); p0[1]=f2bf(v0[1]); p0[2]=f2bf(v0[2]); p0[3]=f2bf(v0[3]);
        p1[0]=f2bf(v1[0]); p1[1]=f2bf(v1[1]); p1[2]=f2bf(v1[2]); p1[3]=f2bf(v1[3]);
        int s = cc ^ (row & 7);
        *(ux4*)&lb[row * BK + s * 8]     = p0;
        *(ux4*)&lb[row * BK + s * 8 + 4] = p1;
      }
    }
    __syncthreads();
    #pragma unroll
    for (int ks = 0; ks < 2; ++ks) {
      short8 af[4], bfg[4];
      #pragma unroll
      for (int t = 0; t < 4; ++t) {
        int arow = wm * 64 + t * 16 + l16;
        int brow = (t & 2) * 32 + wn * 32 + (t & 1) * 16 + l16;
        int cc = (ks * 4 + quad) ^ sw;
        af[t]  = *(const short8*)&la[arow * BK + cc * 8];
        bfg[t] = *(const short8*)&lb[brow * BK + cc * 8];
      }
      #pragma unroll
      for (int mt = 0; mt < 4; ++mt)
        #pragma unroll
        for (int nt = 0; nt < 4; ++nt)
          acc[mt][nt] = __builtin_amdgcn_mfma_f32_16x16x32_bf16(af[mt], bfg[nt], acc[mt][nt], 0, 0, 0);
    }
  }

  if constexpr (MODE == 0) {
    float* of = (float*)o0;
    #pragma unroll
    for (int nt = 0; nt < 4; ++nt) {
      int col = n0 + (nt & 2) * 32 + wn * 32 + (nt & 1) * 16 + l16;
      float bz = bias[col];
      #pragma unroll
      for (int mt = 0; mt < 4; ++mt) {
        int row = m0 + wm * 64 + mt * 16 + quad * 4;
        #pragma unroll
        for (int r = 0; r < 4; ++r)
          of[(size_t)(row + r) * N + col] = acc[mt][nt][r] + bz;
      }
    }
  } else {
    const int which = n0 >> 11;
    const int head  = (n0 >> 7) & 15;
    const int b     = m0 >> 11;
    const int bh    = b * NH + head;
    if (which == 2) {
      #pragma unroll
      for (int nt = 0; nt < 4; ++nt) {
        int dcol = (nt & 2) * 32 + wn * 32 + (nt & 1) * 16 + l16;
        float bz = bias[n0 + dcol];
        #pragma unroll
        for (int mt = 0; mt < 4; ++mt) {
          int srow = (m0 & (S_LEN - 1)) + wm * 64 + mt * 16 + quad * 4;
          ux4 pk;
          #pragma unroll
          for (int r = 0; r < 4; ++r) pk[r] = f2bf(acc[mt][nt][r] + bz);
          *(ux4*)&o2[((size_t)bh * HD + dcol) * S_LEN + srow] = pk;  // V^T
        }
      }
    } else {
      // Q or K with fused RoPE: pair (i, i+64) = acc[..][nt] / acc[..][nt+2]
      u16* buf = (which == 0) ? (u16*)o0 : o1;
      #pragma unroll
      for (int nt = 0; nt < 2; ++nt) {
        int i = wn * 32 + nt * 16 + l16;            // 0..63
        // invf2 = 10000^(-i/64) / (2*pi): angle in revolutions per srow
        float invf2 = exp2f((float)i * -0.20762050594f) * INV2PI;
        float bz1 = bias[n0 + i];
        float bz2 = bias[n0 + i + 64];
        #pragma unroll
        for (int mt = 0; mt < 4; ++mt) {
          int srow = (m0 & (S_LEN - 1)) + wm * 64 + mt * 16 + quad * 4;
          size_t base = ((size_t)bh * S_LEN + srow) * HD + i;
          #pragma unroll
          for (int r = 0; r < 4; ++r) {
            float sn, cs;
            fast_sincos((float)(srow + r) * invf2, sn, cs);
            float v1 = acc[mt][nt][r] + bz1;
            float v2 = acc[mt][nt + 2][r] + bz2;
            buf[base + (size_t)r * HD]      = f2bf(v1 * cs - v2 * sn);
            buf[base + (size_t)r * HD + 64] = f2bf(v2 * cs + v1 * sn);
          }
        }
      }
    }
  }
}

// ---------------------------------------------------------------------------
// Transposed online-softmax tile step with defer-max (T13). S^T in C-layout:
// lane owns q-row=l16, 16 keys = snt*16 + quad*4 + r in registers. Row reduce
// = in-register tree + 2 shuffles. Defer the O-rescale when the tile max is
// within 8 (log2) of the running max (wave-uniform via __all).
// P -> LDS [q][key] stride 72 (R9's in-register-P shuffle variant measured
// +20 us -> reverted; stride-72 spreads q-rows across banks).
// ---------------------------------------------------------------------------
__device__ __forceinline__ void soft_tile_t(fx4 s[4], float& m, float& l, fx4* o,
                                            u16* lp, bool mask, int qrow, int k0,
                                            int l16, int quad)
{
  #pragma unroll
  for (int snt = 0; snt < 4; ++snt)
    #pragma unroll
    for (int r = 0; r < 4; ++r) {
      float v = s[snt][r] * SC2;
      if (mask && (k0 + snt * 16 + quad * 4 + r > qrow)) v = NEG;
      s[snt][r] = v;
    }
  float mx = s[0][0];
  #pragma unroll
  for (int snt = 0; snt < 4; ++snt)
    #pragma unroll
    for (int r = 0; r < 4; ++r) mx = fmaxf(mx, s[snt][r]);
  mx = fmaxf(mx, __shfl_xor(mx, 16, 64));
  mx = fmaxf(mx, __shfl_xor(mx, 32, 64));

  const bool defer = __all(mx <= m + 8.f);   // wave-uniform
  float al = 1.f;
  if (!defer) {
    float mn = fmaxf(m, mx);
    al = exp2f(m - mn);
    m = mn;
  }
  float rs = 0.f;
  #pragma unroll
  for (int snt = 0; snt < 4; ++snt)
    #pragma unroll
    for (int r = 0; r < 4; ++r) {
      float pz = exp2f(s[snt][r] - m);
      s[snt][r] = pz;
      rs += pz;
    }
  rs += __shfl_xor(rs, 16, 64);
  rs += __shfl_xor(rs, 32, 64);
  l = l * al + rs;
  if (!defer) {
    #pragma unroll
    for (int nd = 0; nd < 8; ++nd)
      #pragma unroll
      for (int r = 0; r < 4; ++r) o[nd][r] *= al;
  }
  #pragma unroll
  for (int snt = 0; snt < 4; ++snt) {
    ux4 pk;
    #pragma unroll
    for (int r = 0; r < 4; ++r) pk[r] = f2bf(s[snt][r]);
    *(ux4*)&lp[l16 * 72 + snt * 16 + quad * 4] = pk;   // 8B write
  }
}

// ---------------------------------------------------------------------------
// Flash attention (causal), UNPAIRED q-tiles -- R8-proven body (P in LDS
// stride-72, 3 blocks/CU, setprio, defer-max) with a LOAD-BALANCED decode.
//
// Dispatch model (empirically confirmed: w%8 = XCD): CU slot gets blocks
// w, w+256, w+512(, w+768). Old decode qt=(w>>3)&31 gave ALL of them the
// SAME qt -> per-CU work spanned 4x1..4x32 tile-iters (32x imbalance; R9
// occupancy 20% with the heavy CUs as the wall clock).
// New decode: s=(w>>3)>>5, j=(w>>3)&31:  qt = (s&1) ? 31-j : j.
// CU-slot qts = {j, 31-j, j, 31-j} -> per-CU work == 66 tile-iters, constant.
// Bijection over (bh,qt) holds; XCD bh-grouping (4 bh per XCD L2) unchanged.
// ---------------------------------------------------------------------------
__global__ __launch_bounds__(256, 3)
void attn_kernel(const u16* __restrict__ qbuf, const u16* __restrict__ kbuf,
                 const u16* __restrict__ vtbuf, u16* __restrict__ ctx)
{
  __shared__ u16 lk[64 * 128];     // K tile  [key][d],  swizzled chunks
  __shared__ u16 lv[128 * 64];     // V^T tile [d][key], swizzled chunks
  __shared__ u16 lp[4][16 * 72];   // per-wave P [q][key]
  const int tid = threadIdx.x, lane = tid & 63, wv = tid >> 6;
  const int quad = lane >> 4, l16 = lane & 15;
  const int w = blockIdx.x;
  const int s  = (w >> 3) >> 5;                   // 0..3: bh within XCD group
  const int j  = (w >> 3) & 31;
  const int bh = (w & 7) * 4 + s;                 // XCD-grouped head
  const int qt = (s & 1) ? 31 - j : j;            // balanced q-tile decode
  const int head = bh & 15, b = bh >> 4;
  const int s8 = l16 & 7;          // frag-read swizzle index

  short8 qh[4];
  {
    const size_t q_ = ((size_t)bh * S_LEN + qt * 64 + wv * 16 + l16) * HD;
    #pragma unroll
    for (int kd = 0; kd < 4; ++kd)
      qh[kd] = *(const short8*)&qbuf[q_ + kd * 32 + quad * 8];
  }

  fx4 oh[8] = {};
  float m = NEG, l = 0.f;
  const int qrow = qt * 64 + wv * 16 + l16;

  for (int kt = 0; kt <= qt; ++kt) {
    if (kt) __syncthreads();                 // WAR vs previous compute
    {
      const u16* kg = kbuf + ((size_t)bh * S_LEN + kt * 64) * HD;
      const u16* vg = vtbuf + (size_t)bh * HD * S_LEN + kt * 64;
      #pragma unroll
      for (int i = 0; i < 4; ++i) {          // K tile: 64 rows x 16 chunks
        int c = i * 256 + tid;
        int row = c >> 4, cc = c & 15;
        int g = cc ^ (row & 7);
        gl_lds(kg + (size_t)row * HD + g * 8, &lk[c * 8]);
      }
      #pragma unroll
      for (int i = 0; i < 4; ++i) {          // V^T tile: 128 rows x 8 chunks
        int c = i * 256 + tid;
        int row = c >> 3, cc = c & 7;
        int g = cc ^ (row & 7);
        gl_lds(vg + (size_t)row * S_LEN + g * 8, &lv[c * 8]);
      }
    }
    __syncthreads();                         // RAW: drain stage

    // S^T = K·Q^T
    fx4 sh[4] = {};
    __builtin_amdgcn_s_setprio(1);
    #pragma unroll
    for (int snt = 0; snt < 4; ++snt) {
      #pragma unroll
      for (int kd = 0; kd < 4; ++kd) {
        int cc = (kd * 4 + quad) ^ s8;
        short8 kf = *(const short8*)&lk[(snt * 16 + l16) * 128 + cc * 8];
        sh[snt] = __builtin_amdgcn_mfma_f32_16x16x32_bf16(kf, qh[kd], sh[snt], 0, 0, 0);
      }
    }
    __builtin_amdgcn_s_setprio(0);

    soft_tile_t(sh, m, l, oh, lp[wv], kt == qt, qrow, kt * 64, l16, quad);

    // O^T += V^T·P^T
    __builtin_amdgcn_s_setprio(1);
    #pragma unroll
    for (int kk = 0; kk < 2; ++kk) {
      short8 ph = *(const short8*)&lp[wv][l16 * 72 + kk * 32 + quad * 8];
      #pragma unroll
      for (int nd = 0; nd < 8; ++nd) {
        int cc = (kk * 4 + quad) ^ s8;
        short8 vf = *(const short8*)&lv[(nd * 16 + l16) * 64 + cc * 8];
        oh[nd] = __builtin_amdgcn_mfma_f32_16x16x32_bf16(vf, ph, oh[nd], 0, 0, 0);
      }
    }
    __builtin_amdgcn_s_setprio(0);
  }

  // O^T regs: lane q=l16, d = nd*16 + quad*4 + r  -> 8B packed stores
  {
    float ih = 1.f / l;
    size_t rh = ((size_t)b * S_LEN + qt * 64 + wv * 16 + l16) * DM + head * HD;
    #pragma unroll
    for (int nd = 0; nd < 8; ++nd) {
      ux4 ph;
      #pragma unroll
      for (int r = 0; r < 4; ++r) ph[r] = f2bf(oh[nd][r] * ih);
      *(ux4*)&ctx[rh + nd * 16 + quad * 4] = ph;
    }
  }
}

// ---------------------------------------------------------------------------
extern "C" void kernel_launch(void* const* d_in, const int* in_sizes, int n_in,
                              void* d_out, int out_size, void* d_ws, size_t ws_size,
                              hipStream_t stream)
{
  const float* x    = (const float*)d_in[0];
  const float* Wqkv = (const float*)d_in[2];
  const float* bqkv = (const float*)d_in[3];
  const float* Wout = (const float*)d_in[4];
  const float* bout = (const float*)d_in[5];
  float* out = (float*)d_out;

  constexpr size_t XB_E = (size_t)4096 * 2048;   // 8.39M elems
  constexpr size_t WQ_E = (size_t)6144 * 2048;
  constexpr size_t WO_E = (size_t)2048 * 2048;
  constexpr size_t NEED = (XB_E + WQ_E + WO_E + 3 * XB_E) * 2;  // ~101 MB

  if (ws_size >= NEED) {
    u16* xb  = (u16*)d_ws;
    u16* wqb = xb + XB_E;
    u16* wob = wqb + WQ_E;
    u16* qb  = wob + WO_E;
    u16* kb  = qb + XB_E;
    u16* vb  = kb + XB_E;
    u16* ctx = xb;                 // xb dead after QKV GEMM; reuse for ctx

    cvt3_kernel<<<dim3(24576), 256, 0, stream>>>(x, Wqkv, Wout, xb, wqb, wob);
    gemm_bt<4096, 6144, 2048, 1, true, true><<<dim3(48, 32), 256, 0, stream>>>(
        xb, wqb, bqkv, qb, kb, vb);
    attn_kernel<<<dim3(1024), 256, 0, stream>>>(qb, kb, vb, ctx);
    gemm_bt<4096, 2048, 2048, 0, true, true><<<dim3(16, 32), 256, 0, stream>>>(
        ctx, wob, bout, out, nullptr, nullptr);
  } else {
    // fallback: 48 MiB ws, fused fp32->bf16 staging in GEMMs, ctx in d_out
    u16* qb = (u16*)d_ws;
    u16* kb = qb + XB_E;
    u16* vb = kb + XB_E;
    u16* ctx = (u16*)d_out;
    float* tmpo = (float*)d_ws;   // over dead qb/kb at out-proj time

    gemm_bt<4096, 6144, 2048, 1, false, false><<<dim3(48, 32), 256, 0, stream>>>(
        x, Wqkv, bqkv, qb, kb, vb);
    attn_kernel<<<dim3(1024), 256, 0, stream>>>(qb, kb, vb, ctx);
    gemm_bt<4096, 2048, 2048, 0, true, false><<<dim3(16, 32), 256, 0, stream>>>(
        ctx, Wout, bout, tmpo, nullptr, nullptr);
    hipMemcpyAsync(out, tmpo, (size_t)out_size * sizeof(float),
                   hipMemcpyDeviceToDevice, stream);
  }
}

// Round 11
// 393.478 us; speedup vs baseline: 1.1241x; 1.0424x over previous
//
#include <hip/hip_runtime.h>

typedef unsigned short u16;
typedef __attribute__((ext_vector_type(8))) short short8;
typedef __attribute__((ext_vector_type(4))) float fx4;
typedef __attribute__((ext_vector_type(4))) int ix4;
typedef __attribute__((ext_vector_type(4))) unsigned short ux4;

__device__ __forceinline__ float bf2f(u16 h) {
  union { unsigned u; float f; } a; a.u = ((unsigned)h) << 16; return a.f;
}
__device__ __forceinline__ u16 f2bf(float f) {
  union { float f; unsigned u; } a; a.f = f;
  unsigned u = a.u;
  return (u16)((u + 0x7FFFu + ((u >> 16) & 1u)) >> 16);  // RNE
}

// async global->LDS, 16B per lane. LDS dest must be wave-uniform base + lane*16.
__device__ __forceinline__ void gl_lds(const u16* g, u16* l) {
  __builtin_amdgcn_global_load_lds(
      (const __attribute__((address_space(1))) unsigned*)g,
      (__attribute__((address_space(3))) unsigned*)l, 16, 0, 0);
}

constexpr int S_LEN = 2048;
constexpr int DM = 2048;
constexpr int HD = 128;
constexpr int NH = 16;
constexpr float NEG = -1.0e9f;
constexpr float SC2 = 0.08838834764831845f * 1.4426950408889634f;  // 1/sqrt(128)*log2(e)
constexpr float INV2PI = 0.15915494309189535f;

// HW sin/cos: v_sin/v_cos take revolutions; pre-reduce with fract.
// (R5-R10: absmax unchanged -> verified.)
__device__ __forceinline__ void fast_sincos(float rev_unred, float& sn, float& cs) {
  float rev = rev_unred - floorf(rev_unred);
  sn = __builtin_amdgcn_sinf(rev);
  cs = __builtin_amdgcn_cosf(rev);
}

// ---------------------------------------------------------------------------
// fp32 -> bf16 bulk convert, all three tensors in ONE launch (x, Wqkv, Wout).
// ---------------------------------------------------------------------------
__global__ __launch_bounds__(256)
void cvt3_kernel(const float* __restrict__ x, const float* __restrict__ wq,
                 const float* __restrict__ wo,
                 u16* __restrict__ xb, u16* __restrict__ wqb, u16* __restrict__ wob)
{
  int bid = blockIdx.x;
  const float* in; u16* out; int base;
  if (bid < 8192)       { in = x;  out = xb;  base = bid; }
  else if (bid < 20480) { in = wq; out = wqb; base = bid - 8192; }
  else                  { in = wo; out = wob; base = bid - 20480; }
  size_t idx = (size_t)base * 256 + threadIdx.x;
  fx4 v = *(const fx4*)&in[idx * 4];
  ux4 pk;
  pk[0] = f2bf(v[0]); pk[1] = f2bf(v[1]); pk[2] = f2bf(v[2]); pk[3] = f2bf(v[3]);
  *(ux4*)&out[idx * 4] = pk;
}

// ---------------------------------------------------------------------------
// GEMM: C[M,N] = A[M,K] @ W[N,K]^T + bias (bias fp32)
// MODE 0: fp32 out to o0;  MODE 1: QKV scatter bf16 (o0=Q, o1=K, o2=V^T)
//         with RoPE fused into the Q/K epilogue (HW v_sin/v_cos).
// 2D grid (n fastest): concurrent blocks share one A-panel + few W-panels in
// each XCD L2 -- measured best (R6's XCD column-ownership DOUBLED fetch).
// Keep the proven 2-barrier loop; phased rewrites regressed twice.
// ---------------------------------------------------------------------------
template<int M, int N, int K, int MODE, bool AB16, bool WB16>
__global__ __launch_bounds__(256)
void gemm_bt(const void* __restrict__ Av, const void* __restrict__ Wv,
             const float* __restrict__ bias,
             void* __restrict__ o0, u16* __restrict__ o1, u16* __restrict__ o2)
{
  constexpr int BK = 64;
  __shared__ u16 la[128 * BK];
  __shared__ u16 lb[128 * BK];
  const int tid  = threadIdx.x;
  const int lane = tid & 63;
  const int wv   = tid >> 6;
  const int wm   = wv >> 1, wn = wv & 1;
  const int quad = lane >> 4, l16 = lane & 15;
  const int m0 = blockIdx.y * 128, n0 = blockIdx.x * 128;
  const int sw = l16 & 7;                     // frag-read swizzle (row&7 = l16&7)

  fx4 acc[4][4] = {};

  for (int k0 = 0; k0 < K; k0 += BK) {
    __syncthreads();
    if constexpr (AB16) {
      const u16* ap = (const u16*)Av + (size_t)m0 * K + k0;
      #pragma unroll
      for (int i = 0; i < 4; ++i) {
        int c = i * 256 + tid, row = c >> 3, cc = c & 7;
        int g = cc ^ (row & 7);
        gl_lds(ap + (size_t)row * K + g * 8, &la[c * 8]);
      }
    } else {
      const float* ap = (const float*)Av + (size_t)m0 * K + k0;
      #pragma unroll
      for (int i = 0; i < 4; ++i) {
        int c = i * 256 + tid, row = c >> 3, cc = c & 7;
        fx4 v0 = *(const fx4*)&ap[(size_t)row * K + cc * 8];
        fx4 v1 = *(const fx4*)&ap[(size_t)row * K + cc * 8 + 4];
        ux4 p0, p1;
        p0[0]=f2bf(v0[0]); p0[1]=f2bf(v0[1]); p0[2]=f2bf(v0[2]); p0[3]=f2bf(v0[3]);
        p1[0]=f2bf(v1[0]); p1[1]=f2bf(v1[1]); p1[2]=f2bf(v1[2]); p1[3]=f2bf(v1[3]);
        int s = cc ^ (row & 7);
        *(ux4*)&la[row * BK + s * 8]     = p0;
        *(ux4*)&la[row * BK + s * 8 + 4] = p1;
      }
    }
    if constexpr (WB16) {
      const u16* wp = (const u16*)Wv + (size_t)n0 * K + k0;
      #pragma unroll
      for (int i = 0; i < 4; ++i) {
        int c = i * 256 + tid, row = c >> 3, cc = c & 7;
        int g = cc ^ (row & 7);
        gl_lds(wp + (size_t)row * K + g * 8, &lb[c * 8]);
      }
    } else {
      const float* wp = (const float*)Wv + (size_t)n0 * K + k0;
      #pragma unroll
      for (int i = 0; i < 4; ++i) {
        int c = i * 256 + tid, row = c >> 3, cc = c & 7;
        fx4 v0 = *(const fx4*)&wp[(size_t)row * K + cc * 8];
        fx4 v1 = *(const fx4*)&wp[(size_t)row * K + cc * 8 + 4];
        ux4 p0, p1;
        p0[0]=f2bf(v0[0]); p0[1]=f2bf(v0[1]); p0[2]=f2bf(v0[2]); p0[3]=f2bf(v0[3]);
        p1[0]=f2bf(v1[0]); p1[1]=f2bf(v1[1]); p1[2]=f2bf(v1[2]); p1[3]=f2bf(v1[3]);
        int s = cc ^ (row & 7);
        *(ux4*)&lb[row * BK + s * 8]     = p0;
        *(ux4*)&lb[row * BK + s * 8 + 4] = p1;
      }
    }
    __syncthreads();
    #pragma unroll
    for (int ks = 0; ks < 2; ++ks) {
      short8 af[4], bfg[4];
      #pragma unroll
      for (int t = 0; t < 4; ++t) {
        int arow = wm * 64 + t * 16 + l16;
        int brow = (t & 2) * 32 + wn * 32 + (t & 1) * 16 + l16;
        int cc = (ks * 4 + quad) ^ sw;
        af[t]  = *(const short8*)&la[arow * BK + cc * 8];
        bfg[t] = *(const short8*)&lb[brow * BK + cc * 8];
      }
      #pragma unroll
      for (int mt = 0; mt < 4; ++mt)
        #pragma unroll
        for (int nt = 0; nt < 4; ++nt)
          acc[mt][nt] = __builtin_amdgcn_mfma_f32_16x16x32_bf16(af[mt], bfg[nt], acc[mt][nt], 0, 0, 0);
    }
  }

  if constexpr (MODE == 0) {
    float* of = (float*)o0;
    #pragma unroll
    for (int nt = 0; nt < 4; ++nt) {
      int col = n0 + (nt & 2) * 32 + wn * 32 + (nt & 1) * 16 + l16;
      float bz = bias[col];
      #pragma unroll
      for (int mt = 0; mt < 4; ++mt) {
        int row = m0 + wm * 64 + mt * 16 + quad * 4;
        #pragma unroll
        for (int r = 0; r < 4; ++r)
          of[(size_t)(row + r) * N + col] = acc[mt][nt][r] + bz;
      }
    }
  } else {
    const int which = n0 >> 11;
    const int head  = (n0 >> 7) & 15;
    const int b     = m0 >> 11;
    const int bh    = b * NH + head;
    if (which == 2) {
      #pragma unroll
      for (int nt = 0; nt < 4; ++nt) {
        int dcol = (nt & 2) * 32 + wn * 32 + (nt & 1) * 16 + l16;
        float bz = bias[n0 + dcol];
        #pragma unroll
        for (int mt = 0; mt < 4; ++mt) {
          int srow = (m0 & (S_LEN - 1)) + wm * 64 + mt * 16 + quad * 4;
          ux4 pk;
          #pragma unroll
          for (int r = 0; r < 4; ++r) pk[r] = f2bf(acc[mt][nt][r] + bz);
          *(ux4*)&o2[((size_t)bh * HD + dcol) * S_LEN + srow] = pk;  // V^T
        }
      }
    } else {
      // Q or K with fused RoPE: pair (i, i+64) = acc[..][nt] / acc[..][nt+2]
      u16* buf = (which == 0) ? (u16*)o0 : o1;
      #pragma unroll
      for (int nt = 0; nt < 2; ++nt) {
        int i = wn * 32 + nt * 16 + l16;            // 0..63
        // invf2 = 10000^(-i/64) / (2*pi): angle in revolutions per srow
        float invf2 = exp2f((float)i * -0.20762050594f) * INV2PI;
        float bz1 = bias[n0 + i];
        float bz2 = bias[n0 + i + 64];
        #pragma unroll
        for (int mt = 0; mt < 4; ++mt) {
          int srow = (m0 & (S_LEN - 1)) + wm * 64 + mt * 16 + quad * 4;
          size_t base = ((size_t)bh * S_LEN + srow) * HD + i;
          #pragma unroll
          for (int r = 0; r < 4; ++r) {
            float sn, cs;
            fast_sincos((float)(srow + r) * invf2, sn, cs);
            float v1 = acc[mt][nt][r] + bz1;
            float v2 = acc[mt][nt + 2][r] + bz2;
            buf[base + (size_t)r * HD]      = f2bf(v1 * cs - v2 * sn);
            buf[base + (size_t)r * HD + 64] = f2bf(v2 * cs + v1 * sn);
          }
        }
      }
    }
  }
}

// ---------------------------------------------------------------------------
// Transposed online-softmax tile step with defer-max (T13). S^T in C-layout:
// lane owns q-row=l16, 16 keys = snt*16 + quad*4 + r in registers. Row reduce
// = in-register tree + 2 shuffles. Defer the O-rescale when the tile max is
// within 8 (log2) of the running max (wave-uniform via __all).
// P -> LDS [q][key] stride 72 (spreads q-rows across banks; stride-64 and
// in-register-P variants both measured worse).
// ---------------------------------------------------------------------------
__device__ __forceinline__ void soft_tile_t(fx4 s[4], float& m, float& l, fx4* o,
                                            u16* lp, bool mask, int qrow, int k0,
                                            int l16, int quad)
{
  #pragma unroll
  for (int snt = 0; snt < 4; ++snt)
    #pragma unroll
    for (int r = 0; r < 4; ++r) {
      float v = s[snt][r] * SC2;
      if (mask && (k0 + snt * 16 + quad * 4 + r > qrow)) v = NEG;
      s[snt][r] = v;
    }
  float mx = s[0][0];
  #pragma unroll
  for (int snt = 0; snt < 4; ++snt)
    #pragma unroll
    for (int r = 0; r < 4; ++r) mx = fmaxf(mx, s[snt][r]);
  mx = fmaxf(mx, __shfl_xor(mx, 16, 64));
  mx = fmaxf(mx, __shfl_xor(mx, 32, 64));

  const bool defer = __all(mx <= m + 8.f);   // wave-uniform
  float al = 1.f;
  if (!defer) {
    float mn = fmaxf(m, mx);
    al = exp2f(m - mn);
    m = mn;
  }
  float rs = 0.f;
  #pragma unroll
  for (int snt = 0; snt < 4; ++snt)
    #pragma unroll
    for (int r = 0; r < 4; ++r) {
      float pz = exp2f(s[snt][r] - m);
      s[snt][r] = pz;
      rs += pz;
    }
  rs += __shfl_xor(rs, 16, 64);
  rs += __shfl_xor(rs, 32, 64);
  l = l * al + rs;
  if (!defer) {
    #pragma unroll
    for (int nd = 0; nd < 8; ++nd)
      #pragma unroll
      for (int r = 0; r < 4; ++r) o[nd][r] *= al;
  }
  #pragma unroll
  for (int snt = 0; snt < 4; ++snt) {
    ux4 pk;
    #pragma unroll
    for (int r = 0; r < 4; ++r) pk[r] = f2bf(s[snt][r]);
    *(ux4*)&lp[l16 * 72 + snt * 16 + quad * 4] = pk;   // 8B write
  }
}

// ---------------------------------------------------------------------------
// Flash attention (causal), QBLK=128 (8 waves x 16 q-rows), per-wave body
// IDENTICAL to the R10-proven kernel -- only the wave count and decode change.
// Halves staged K/V bytes and barriers per unit work (272 vs 528 tile-stages
// per bh) and raises residency to 16 waves/CU (512 blocks = exactly 2/CU,
// 50 KB LDS, zero dispatch tail).
// Causal gating: wave wv's last tile myKt = 2qt + (wv>>2); compute is skipped
// (wave-uniform) for kt > myKt; barriers stay outside the guard. Only the
// final kt has half the waves idle.
// Decode: w&7 = XCD (confirmed), s=(w>>3)>>4 in 0..3 -> bh=(w&7)*4+s;
// j=(w>>3)&15. CU slot gets w and w+256 -> s and s+2, so balance must flip
// on BIT 1 of s: qt = ((s>>1)&1) ? 15-j : j. Per-CU work = 36 tile-iters,
// constant; bijection holds; 4-bh-per-XCD L2 grouping kept.
// ---------------------------------------------------------------------------
__global__ __launch_bounds__(512, 4)
void attn_kernel(const u16* __restrict__ qbuf, const u16* __restrict__ kbuf,
                 const u16* __restrict__ vtbuf, u16* __restrict__ ctx)
{
  __shared__ u16 lk[64 * 128];     // K tile  [key][d],  swizzled chunks (16 KiB)
  __shared__ u16 lv[128 * 64];     // V^T tile [d][key], swizzled chunks (16 KiB)
  __shared__ u16 lp[8][16 * 72];   // per-wave P [q][key] (18 KiB)
  const int tid = threadIdx.x, lane = tid & 63, wv = tid >> 6;
  const int quad = lane >> 4, l16 = lane & 15;
  const int w = blockIdx.x;
  const int s  = (w >> 3) >> 4;                   // 0..3: bh within XCD group
  const int j  = (w >> 3) & 15;
  const int bh = (w & 7) * 4 + s;                 // XCD-grouped head
  const int qt = ((s >> 1) & 1) ? 15 - j : j;     // balanced q-tile decode
  const int head = bh & 15, b = bh >> 4;
  const int s8 = l16 & 7;          // frag-read swizzle index

  short8 qh[4];
  {
    const size_t q_ = ((size_t)bh * S_LEN + qt * 128 + wv * 16 + l16) * HD;
    #pragma unroll
    for (int kd = 0; kd < 4; ++kd)
      qh[kd] = *(const short8*)&qbuf[q_ + kd * 32 + quad * 8];
  }

  fx4 oh[8] = {};
  float m = NEG, l = 0.f;
  const int qrow = qt * 128 + wv * 16 + l16;
  const int myKt = 2 * qt + (wv >> 2);            // wave's last (masked) tile
  const int ktEnd = 2 * qt + 1;

  for (int kt = 0; kt <= ktEnd; ++kt) {
    if (kt) __syncthreads();                 // WAR vs previous compute
    {
      const u16* kg = kbuf + ((size_t)bh * S_LEN + kt * 64) * HD;
      const u16* vg = vtbuf + (size_t)bh * HD * S_LEN + kt * 64;
      #pragma unroll
      for (int i = 0; i < 2; ++i) {          // K tile: 64 rows x 16 chunks
        int c = i * 512 + tid;
        int row = c >> 4, cc = c & 15;
        int g = cc ^ (row & 7);
        gl_lds(kg + (size_t)row * HD + g * 8, &lk[c * 8]);
      }
      #pragma unroll
      for (int i = 0; i < 2; ++i) {          // V^T tile: 128 rows x 8 chunks
        int c = i * 512 + tid;
        int row = c >> 3, cc = c & 7;
        int g = cc ^ (row & 7);
        gl_lds(vg + (size_t)row * S_LEN + g * 8, &lv[c * 8]);
      }
    }
    __syncthreads();                         // RAW: drain stage

    if (kt <= myKt) {                        // wave-uniform causal gate
      // S^T = K·Q^T
      fx4 sh[4] = {};
      __builtin_amdgcn_s_setprio(1);
      #pragma unroll
      for (int snt = 0; snt < 4; ++snt) {
        #pragma unroll
        for (int kd = 0; kd < 4; ++kd) {
          int cc = (kd * 4 + quad) ^ s8;
          short8 kf = *(const short8*)&lk[(snt * 16 + l16) * 128 + cc * 8];
          sh[snt] = __builtin_amdgcn_mfma_f32_16x16x32_bf16(kf, qh[kd], sh[snt], 0, 0, 0);
        }
      }
      __builtin_amdgcn_s_setprio(0);

      soft_tile_t(sh, m, l, oh, lp[wv], kt == myKt, qrow, kt * 64, l16, quad);

      // O^T += V^T·P^T
      __builtin_amdgcn_s_setprio(1);
      #pragma unroll
      for (int kk = 0; kk < 2; ++kk) {
        short8 ph = *(const short8*)&lp[wv][l16 * 72 + kk * 32 + quad * 8];
        #pragma unroll
        for (int nd = 0; nd < 8; ++nd) {
          int cc = (kk * 4 + quad) ^ s8;
          short8 vf = *(const short8*)&lv[(nd * 16 + l16) * 64 + cc * 8];
          oh[nd] = __builtin_amdgcn_mfma_f32_16x16x32_bf16(vf, ph, oh[nd], 0, 0, 0);
        }
      }
      __builtin_amdgcn_s_setprio(0);
    }
  }

  // O^T regs: lane q=l16, d = nd*16 + quad*4 + r  -> 8B packed stores
  {
    float ih = 1.f / l;
    size_t rh = ((size_t)b * S_LEN + qt * 128 + wv * 16 + l16) * DM + head * HD;
    #pragma unroll
    for (int nd = 0; nd < 8; ++nd) {
      ux4 ph;
      #pragma unroll
      for (int r = 0; r < 4; ++r) ph[r] = f2bf(oh[nd][r] * ih);
      *(ux4*)&ctx[rh + nd * 16 + quad * 4] = ph;
    }
  }
}

// ---------------------------------------------------------------------------
extern "C" void kernel_launch(void* const* d_in, const int* in_sizes, int n_in,
                              void* d_out, int out_size, void* d_ws, size_t ws_size,
                              hipStream_t stream)
{
  const float* x    = (const float*)d_in[0];
  const float* Wqkv = (const float*)d_in[2];
  const float* bqkv = (const float*)d_in[3];
  const float* Wout = (const float*)d_in[4];
  const float* bout = (const float*)d_in[5];
  float* out = (float*)d_out;

  constexpr size_t XB_E = (size_t)4096 * 2048;   // 8.39M elems
  constexpr size_t WQ_E = (size_t)6144 * 2048;
  constexpr size_t WO_E = (size_t)2048 * 2048;
  constexpr size_t NEED = (XB_E + WQ_E + WO_E + 3 * XB_E) * 2;  // ~101 MB

  if (ws_size >= NEED) {
    u16* xb  = (u16*)d_ws;
    u16* wqb = xb + XB_E;
    u16* wob = wqb + WQ_E;
    u16* qb  = wob + WO_E;
    u16* kb  = qb + XB_E;
    u16* vb  = kb + XB_E;
    u16* ctx = xb;                 // xb dead after QKV GEMM; reuse for ctx

    cvt3_kernel<<<dim3(24576), 256, 0, stream>>>(x, Wqkv, Wout, xb, wqb, wob);
    gemm_bt<4096, 6144, 2048, 1, true, true><<<dim3(48, 32), 256, 0, stream>>>(
        xb, wqb, bqkv, qb, kb, vb);
    attn_kernel<<<dim3(512), 512, 0, stream>>>(qb, kb, vb, ctx);
    gemm_bt<4096, 2048, 2048, 0, true, true><<<dim3(16, 32), 256, 0, stream>>>(
        ctx, wob, bout, out, nullptr, nullptr);
  } else {
    // fallback: 48 MiB ws, fused fp32->bf16 staging in GEMMs, ctx in d_out
    u16* qb = (u16*)d_ws;
    u16* kb = qb + XB_E;
    u16* vb = kb + XB_E;
    u16* ctx = (u16*)d_out;
    float* tmpo = (float*)d_ws;   // over dead qb/kb at out-proj time

    gemm_bt<4096, 6144, 2048, 1, false, false><<<dim3(48, 32), 256, 0, stream>>>(
        x, Wqkv, bqkv, qb, kb, vb);
    attn_kernel<<<dim3(512), 512, 0, stream>>>(qb, kb, vb, ctx);
    gemm_bt<4096, 2048, 2048, 0, true, false><<<dim3(16, 32), 256, 0, stream>>>(
        ctx, Wout, bout, tmpo, nullptr, nullptr);
    hipMemcpyAsync(out, tmpo, (size_t)out_size * sizeof(float),
                   hipMemcpyDeviceToDevice, stream);
  }
}

// Round 13
// 389.641 us; speedup vs baseline: 1.1352x; 1.0098x over previous
//
#include <hip/hip_runtime.h>

typedef unsigned short u16;
typedef __attribute__((ext_vector_type(8))) short short8;
typedef __attribute__((ext_vector_type(4))) float fx4;
typedef __attribute__((ext_vector_type(4))) int ix4;
typedef __attribute__((ext_vector_type(4))) unsigned short ux4;   // 8 B
typedef __attribute__((ext_vector_type(8))) unsigned short ux8;   // 16 B

__device__ __forceinline__ float bf2f(u16 h) {
  union { unsigned u; float f; } a; a.u = ((unsigned)h) << 16; return a.f;
}
__device__ __forceinline__ u16 f2bf(float f) {
  union { float f; unsigned u; } a; a.f = f;
  unsigned u = a.u;
  return (u16)((u + 0x7FFFu + ((u >> 16) & 1u)) >> 16);  // RNE
}

// async global->LDS, 16B per lane. LDS dest must be wave-uniform base + lane*16.
__device__ __forceinline__ void gl_lds(const u16* g, u16* l) {
  __builtin_amdgcn_global_load_lds(
      (const __attribute__((address_space(1))) unsigned*)g,
      (__attribute__((address_space(3))) unsigned*)l, 16, 0, 0);
}

constexpr int S_LEN = 2048;
constexpr int DM = 2048;
constexpr int HD = 128;
constexpr int NH = 16;
constexpr float NEG = -1.0e9f;
constexpr float SC2 = 0.08838834764831845f * 1.4426950408889634f;  // 1/sqrt(128)*log2(e)
constexpr float INV2PI = 0.15915494309189535f;

// HW sin/cos: v_sin/v_cos take revolutions; pre-reduce with fract.
// (R5-R11: absmax unchanged -> verified.)
__device__ __forceinline__ void fast_sincos(float rev_unred, float& sn, float& cs) {
  float rev = rev_unred - floorf(rev_unred);
  sn = __builtin_amdgcn_sinf(rev);
  cs = __builtin_amdgcn_cosf(rev);
}

// ---------------------------------------------------------------------------
// fp32 -> bf16 bulk convert, all three tensors in ONE launch (x, Wqkv, Wout).
// ---------------------------------------------------------------------------
__global__ __launch_bounds__(256)
void cvt3_kernel(const float* __restrict__ x, const float* __restrict__ wq,
                 const float* __restrict__ wo,
                 u16* __restrict__ xb, u16* __restrict__ wqb, u16* __restrict__ wob)
{
  int bid = blockIdx.x;
  const float* in; u16* out; int base;
  if (bid < 8192)       { in = x;  out = xb;  base = bid; }
  else if (bid < 20480) { in = wq; out = wqb; base = bid - 8192; }
  else                  { in = wo; out = wob; base = bid - 20480; }
  size_t idx = (size_t)base * 256 + threadIdx.x;
  fx4 v = *(const fx4*)&in[idx * 4];
  ux4 pk;
  pk[0] = f2bf(v[0]); pk[1] = f2bf(v[1]); pk[2] = f2bf(v[2]); pk[3] = f2bf(v[3]);
  *(ux4*)&out[idx * 4] = pk;
}

// ---------------------------------------------------------------------------
// GEMM: C[M,N] = A[M,K] @ W[N,K]^T + bias (bias fp32)
// MODE 0: fp32 out to o0;  MODE 1: QKV scatter bf16 (o0=Q, o1=K, o2=V^T)
//         with RoPE fused into the Q/K epilogue (HW v_sin/v_cos).
// 2D grid (n fastest): concurrent blocks share one A-panel + few W-panels in
// each XCD L2 -- measured best (R6's XCD column-ownership DOUBLED fetch).
// Keep the proven 2-barrier loop; phased rewrites regressed twice.
// ---------------------------------------------------------------------------
template<int M, int N, int K, int MODE, bool AB16, bool WB16>
__global__ __launch_bounds__(256)
void gemm_bt(const void* __restrict__ Av, const void* __restrict__ Wv,
             const float* __restrict__ bias,
             void* __restrict__ o0, u16* __restrict__ o1, u16* __restrict__ o2)
{
  constexpr int BK = 64;
  __shared__ u16 la[128 * BK];
  __shared__ u16 lb[128 * BK];
  const int tid  = threadIdx.x;
  const int lane = tid & 63;
  const int wv   = tid >> 6;
  const int wm   = wv >> 1, wn = wv & 1;
  const int quad = lane >> 4, l16 = lane & 15;
  const int m0 = blockIdx.y * 128, n0 = blockIdx.x * 128;
  const int sw = l16 & 7;                     // frag-read swizzle (row&7 = l16&7)

  fx4 acc[4][4] = {};

  for (int k0 = 0; k0 < K; k0 += BK) {
    __syncthreads();
    if constexpr (AB16) {
      const u16* ap = (const u16*)Av + (size_t)m0 * K + k0;
      #pragma unroll
      for (int i = 0; i < 4; ++i) {
        int c = i * 256 + tid, row = c >> 3, cc = c & 7;
        int g = cc ^ (row & 7);
        gl_lds(ap + (size_t)row * K + g * 8, &la[c * 8]);
      }
    } else {
      const float* ap = (const float*)Av + (size_t)m0 * K + k0;
      #pragma unroll
      for (int i = 0; i < 4; ++i) {
        int c = i * 256 + tid, row = c >> 3, cc = c & 7;
        fx4 v0 = *(const fx4*)&ap[(size_t)row * K + cc * 8];
        fx4 v1 = *(const fx4*)&ap[(size_t)row * K + cc * 8 + 4];
        ux4 p0, p1;
        p0[0]=f2bf(v0[0]); p0[1]=f2bf(v0[1]); p0[2]=f2bf(v0[2]); p0[3]=f2bf(v0[3]);
        p1[0]=f2bf(v1[0]); p1[1]=f2bf(v1[1]); p1[2]=f2bf(v1[2]); p1[3]=f2bf(v1[3]);
        int s = cc ^ (row & 7);
        *(ux4*)&la[row * BK + s * 8]     = p0;
        *(ux4*)&la[row * BK + s * 8 + 4] = p1;
      }
    }
    if constexpr (WB16) {
      const u16* wp = (const u16*)Wv + (size_t)n0 * K + k0;
      #pragma unroll
      for (int i = 0; i < 4; ++i) {
        int c = i * 256 + tid, row = c >> 3, cc = c & 7;
        int g = cc ^ (row & 7);
        gl_lds(wp + (size_t)row * K + g * 8, &lb[c * 8]);
      }
    } else {
      const float* wp = (const float*)Wv + (size_t)n0 * K + k0;
      #pragma unroll
      for (int i = 0; i < 4; ++i) {
        int c = i * 256 + tid, row = c >> 3, cc = c & 7;
        fx4 v0 = *(const fx4*)&wp[(size_t)row * K + cc * 8];
        fx4 v1 = *(const fx4*)&wp[(size_t)row * K + cc * 8 + 4];
        ux4 p0, p1;
        p0[0]=f2bf(v0[0]); p0[1]=f2bf(v0[1]); p0[2]=f2bf(v0[2]); p0[3]=f2bf(v0[3]);
        p1[0]=f2bf(v1[0]); p1[1]=f2bf(v1[1]); p1[2]=f2bf(v1[2]); p1[3]=f2bf(v1[3]);
        int s = cc ^ (row & 7);
        *(ux4*)&lb[row * BK + s * 8]     = p0;
        *(ux4*)&lb[row * BK + s * 8 + 4] = p1;
      }
    }
    __syncthreads();
    #pragma unroll
    for (int ks = 0; ks < 2; ++ks) {
      short8 af[4], bfg[4];
      #pragma unroll
      for (int t = 0; t < 4; ++t) {
        int arow = wm * 64 + t * 16 + l16;
        int brow = (t & 2) * 32 + wn * 32 + (t & 1) * 16 + l16;
        int cc = (ks * 4 + quad) ^ sw;
        af[t]  = *(const short8*)&la[arow * BK + cc * 8];
        bfg[t] = *(const short8*)&lb[brow * BK + cc * 8];
      }
      #pragma unroll
      for (int mt = 0; mt < 4; ++mt)
        #pragma unroll
        for (int nt = 0; nt < 4; ++nt)
          acc[mt][nt] = __builtin_amdgcn_mfma_f32_16x16x32_bf16(af[mt], bfg[nt], acc[mt][nt], 0, 0, 0);
    }
  }

  if constexpr (MODE == 0) {
    float* of = (float*)o0;
    #pragma unroll
    for (int nt = 0; nt < 4; ++nt) {
      int col = n0 + (nt & 2) * 32 + wn * 32 + (nt & 1) * 16 + l16;
      float bz = bias[col];
      #pragma unroll
      for (int mt = 0; mt < 4; ++mt) {
        int row = m0 + wm * 64 + mt * 16 + quad * 4;
        #pragma unroll
        for (int r = 0; r < 4; ++r)
          of[(size_t)(row + r) * N + col] = acc[mt][nt][r] + bz;
      }
    }
  } else {
    const int which = n0 >> 11;
    const int head  = (n0 >> 7) & 15;
    const int b     = m0 >> 11;
    const int bh    = b * NH + head;
    if (which == 2) {
      #pragma unroll
      for (int nt = 0; nt < 4; ++nt) {
        int dcol = (nt & 2) * 32 + wn * 32 + (nt & 1) * 16 + l16;
        float bz = bias[n0 + dcol];
        #pragma unroll
        for (int mt = 0; mt < 4; ++mt) {
          int srow = (m0 & (S_LEN - 1)) + wm * 64 + mt * 16 + quad * 4;
          ux4 pk;
          #pragma unroll
          for (int r = 0; r < 4; ++r) pk[r] = f2bf(acc[mt][nt][r] + bz);
          *(ux4*)&o2[((size_t)bh * HD + dcol) * S_LEN + srow] = pk;  // V^T
        }
      }
    } else {
      // Q or K with fused RoPE: pair (i, i+64) = acc[..][nt] / acc[..][nt+2]
      u16* buf = (which == 0) ? (u16*)o0 : o1;
      #pragma unroll
      for (int nt = 0; nt < 2; ++nt) {
        int i = wn * 32 + nt * 16 + l16;            // 0..63
        // invf2 = 10000^(-i/64) / (2*pi): angle in revolutions per srow
        float invf2 = exp2f((float)i * -0.20762050594f) * INV2PI;
        float bz1 = bias[n0 + i];
        float bz2 = bias[n0 + i + 64];
        #pragma unroll
        for (int mt = 0; mt < 4; ++mt) {
          int srow = (m0 & (S_LEN - 1)) + wm * 64 + mt * 16 + quad * 4;
          size_t base = ((size_t)bh * S_LEN + srow) * HD + i;
          #pragma unroll
          for (int r = 0; r < 4; ++r) {
            float sn, cs;
            fast_sincos((float)(srow + r) * invf2, sn, cs);
            float v1 = acc[mt][nt][r] + bz1;
            float v2 = acc[mt][nt + 2][r] + bz2;
            buf[base + (size_t)r * HD]      = f2bf(v1 * cs - v2 * sn);
            buf[base + (size_t)r * HD + 64] = f2bf(v2 * cs + v1 * sn);
          }
        }
      }
    }
  }
}

// ---------------------------------------------------------------------------
// Transposed online-softmax tile step with defer-max (T13). S^T in C-layout:
// lane owns q-row=l16, 16 keys = snt*16 + quad*4 + r in registers. Row reduce
// = in-register tree + 2 shuffles. Defer the O-rescale when the tile max is
// within 8 (log2) of the running max (wave-uniform via __all).
// P -> LDS [q][key] stride 72 (spreads q-rows across banks; stride-64 and
// in-register-P variants both measured worse).
// ---------------------------------------------------------------------------
__device__ __forceinline__ void soft_tile_t(fx4 s[4], float& m, float& l, fx4* o,
                                            u16* lp, bool mask, int qrow, int k0,
                                            int l16, int quad)
{
  #pragma unroll
  for (int snt = 0; snt < 4; ++snt)
    #pragma unroll
    for (int r = 0; r < 4; ++r) {
      float v = s[snt][r] * SC2;
      if (mask && (k0 + snt * 16 + quad * 4 + r > qrow)) v = NEG;
      s[snt][r] = v;
    }
  float mx = s[0][0];
  #pragma unroll
  for (int snt = 0; snt < 4; ++snt)
    #pragma unroll
    for (int r = 0; r < 4; ++r) mx = fmaxf(mx, s[snt][r]);
  mx = fmaxf(mx, __shfl_xor(mx, 16, 64));
  mx = fmaxf(mx, __shfl_xor(mx, 32, 64));

  const bool defer = __all(mx <= m + 8.f);   // wave-uniform
  float al = 1.f;
  if (!defer) {
    float mn = fmaxf(m, mx);
    al = exp2f(m - mn);
    m = mn;
  }
  float rs = 0.f;
  #pragma unroll
  for (int snt = 0; snt < 4; ++snt)
    #pragma unroll
    for (int r = 0; r < 4; ++r) {
      float pz = exp2f(s[snt][r] - m);
      s[snt][r] = pz;
      rs += pz;
    }
  rs += __shfl_xor(rs, 16, 64);
  rs += __shfl_xor(rs, 32, 64);
  l = l * al + rs;
  if (!defer) {
    #pragma unroll
    for (int nd = 0; nd < 8; ++nd)
      #pragma unroll
      for (int r = 0; r < 4; ++r) o[nd][r] *= al;
  }
  #pragma unroll
  for (int snt = 0; snt < 4; ++snt) {
    ux4 pk;
    #pragma unroll
    for (int r = 0; r < 4; ++r) pk[r] = f2bf(s[snt][r]);
    *(ux4*)&lp[l16 * 72 + snt * 16 + quad * 4] = pk;   // 8B write
  }
}

// ---------------------------------------------------------------------------
// Flash attention (causal), QBLK=128 (8 waves x 16 q-rows) -- R11-proven
// structure (balanced decode, XCD-grouped bh, setprio, defer-max) + T14
// async-STAGE split: tile kt+1's global loads are issued into REGISTERS at
// the top of iteration kt (before compute), hiding their latency under
// QK+softmax+PV; after the read-barrier they are ds_written to the single
// LDS buffer, then the write-barrier publishes them.
// R12 BUGFIX: staging regs are ux8 (8 x u16 = 16 B) -- R12's ux4 was 8 B,
// moving only half of each chunk (upper half = LDS garbage -> NaN).
// ---------------------------------------------------------------------------
__global__ __launch_bounds__(512, 4)
void attn_kernel(const u16* __restrict__ qbuf, const u16* __restrict__ kbuf,
                 const u16* __restrict__ vtbuf, u16* __restrict__ ctx)
{
  __shared__ u16 lk[64 * 128];     // K tile  [key][d],  swizzled chunks (16 KiB)
  __shared__ u16 lv[128 * 64];     // V^T tile [d][key], swizzled chunks (16 KiB)
  __shared__ u16 lp[8][16 * 72];   // per-wave P [q][key] (18 KiB)
  const int tid = threadIdx.x, lane = tid & 63, wv = tid >> 6;
  const int quad = lane >> 4, l16 = lane & 15;
  const int w = blockIdx.x;
  const int s  = (w >> 3) >> 4;                   // 0..3: bh within XCD group
  const int j  = (w >> 3) & 15;
  const int bh = (w & 7) * 4 + s;                 // XCD-grouped head
  const int qt = ((s >> 1) & 1) ? 15 - j : j;     // balanced q-tile decode
  const int head = bh & 15, b = bh >> 4;
  const int s8 = l16 & 7;          // frag-read swizzle index

  short8 qh[4];
  {
    const size_t q_ = ((size_t)bh * S_LEN + qt * 128 + wv * 16 + l16) * HD;
    #pragma unroll
    for (int kd = 0; kd < 4; ++kd)
      qh[kd] = *(const short8*)&qbuf[q_ + kd * 32 + quad * 8];
  }

  fx4 oh[8] = {};
  float m = NEG, l = 0.f;
  const int qrow = qt * 128 + wv * 16 + l16;
  const int myKt = 2 * qt + (wv >> 2);            // wave's last (masked) tile
  const int ktEnd = 2 * qt + 1;

  // T14 staging registers: 2x16B K + 2x16B V per thread
  ux8 kreg[2], vreg[2];
  const u16* kbase = kbuf + (size_t)bh * S_LEN * HD;
  const u16* vbase = vtbuf + (size_t)bh * HD * S_LEN;

  // issue loads for tile kt into kreg/vreg (global src carries the swizzle)
  auto load_tile = [&](int kt) {
    const u16* kg = kbase + (size_t)kt * 64 * HD;
    const u16* vg = vbase + kt * 64;
    #pragma unroll
    for (int i = 0; i < 2; ++i) {            // K tile: 64 rows x 16 chunks
      int c = i * 512 + tid;
      int row = c >> 4, cc = c & 15;
      int g = cc ^ (row & 7);
      kreg[i] = *(const ux8*)&kg[(size_t)row * HD + g * 8];
    }
    #pragma unroll
    for (int i = 0; i < 2; ++i) {            // V^T tile: 128 rows x 8 chunks
      int c = i * 512 + tid;
      int row = c >> 3, cc = c & 7;
      int g = cc ^ (row & 7);
      vreg[i] = *(const ux8*)&vg[(size_t)row * S_LEN + g * 8];
    }
  };
  // publish staged regs to LDS (compiler inserts the vmcnt wait)
  auto write_tile = [&]() {
    #pragma unroll
    for (int i = 0; i < 2; ++i) { int c = i * 512 + tid; *(ux8*)&lk[c * 8] = kreg[i]; }
    #pragma unroll
    for (int i = 0; i < 2; ++i) { int c = i * 512 + tid; *(ux8*)&lv[c * 8] = vreg[i]; }
  };

  load_tile(0);
  write_tile();
  __syncthreads();                           // tile 0 visible

  for (int kt = 0; kt <= ktEnd; ++kt) {
    const bool more = (kt < ktEnd);          // block-uniform
    if (more) load_tile(kt + 1);             // issue early: latency hides
                                             // under the compute below
    if (kt <= myKt) {                        // wave-uniform causal gate
      // S^T = K·Q^T
      fx4 sh[4] = {};
      __builtin_amdgcn_s_setprio(1);
      #pragma unroll
      for (int snt = 0; snt < 4; ++snt) {
        #pragma unroll
        for (int kd = 0; kd < 4; ++kd) {
          int cc = (kd * 4 + quad) ^ s8;
          short8 kf = *(const short8*)&lk[(snt * 16 + l16) * 128 + cc * 8];
          sh[snt] = __builtin_amdgcn_mfma_f32_16x16x32_bf16(kf, qh[kd], sh[snt], 0, 0, 0);
        }
      }
      __builtin_amdgcn_s_setprio(0);

      soft_tile_t(sh, m, l, oh, lp[wv], kt == myKt, qrow, kt * 64, l16, quad);

      // O^T += V^T·P^T
      __builtin_amdgcn_s_setprio(1);
      #pragma unroll
      for (int kk = 0; kk < 2; ++kk) {
        short8 ph = *(const short8*)&lp[wv][l16 * 72 + kk * 32 + quad * 8];
        #pragma unroll
        for (int nd = 0; nd < 8; ++nd) {
          int cc = (kk * 4 + quad) ^ s8;
          short8 vf = *(const short8*)&lv[(nd * 16 + l16) * 64 + cc * 8];
          oh[nd] = __builtin_amdgcn_mfma_f32_16x16x32_bf16(vf, ph, oh[nd], 0, 0, 0);
        }
      }
      __builtin_amdgcn_s_setprio(0);
    }

    __syncthreads();                         // all reads of tile kt done
    if (more) {
      write_tile();                          // publish tile kt+1
      __syncthreads();                       // visible before next compute
    }
  }

  // O^T regs: lane q=l16, d = nd*16 + quad*4 + r  -> 8B packed stores
  {
    float ih = 1.f / l;
    size_t rh = ((size_t)b * S_LEN + qt * 128 + wv * 16 + l16) * DM + head * HD;
    #pragma unroll
    for (int nd = 0; nd < 8; ++nd) {
      ux4 ph;
      #pragma unroll
      for (int r = 0; r < 4; ++r) ph[r] = f2bf(oh[nd][r] * ih);
      *(ux4*)&ctx[rh + nd * 16 + quad * 4] = ph;
    }
  }
}

// ---------------------------------------------------------------------------
extern "C" void kernel_launch(void* const* d_in, const int* in_sizes, int n_in,
                              void* d_out, int out_size, void* d_ws, size_t ws_size,
                              hipStream_t stream)
{
  const float* x    = (const float*)d_in[0];
  const float* Wqkv = (const float*)d_in[2];
  const float* bqkv = (const float*)d_in[3];
  const float* Wout = (const float*)d_in[4];
  const float* bout = (const float*)d_in[5];
  float* out = (float*)d_out;

  constexpr size_t XB_E = (size_t)4096 * 2048;   // 8.39M elems
  constexpr size_t WQ_E = (size_t)6144 * 2048;
  constexpr size_t WO_E = (size_t)2048 * 2048;
  constexpr size_t NEED = (XB_E + WQ_E + WO_E + 3 * XB_E) * 2;  // ~101 MB

  if (ws_size >= NEED) {
    u16* xb  = (u16*)d_ws;
    u16* wqb = xb + XB_E;
    u16* wob = wqb + WQ_E;
    u16* qb  = wob + WO_E;
    u16* kb  = qb + XB_E;
    u16* vb  = kb + XB_E;
    u16* ctx = xb;                 // xb dead after QKV GEMM; reuse for ctx

    cvt3_kernel<<<dim3(24576), 256, 0, stream>>>(x, Wqkv, Wout, xb, wqb, wob);
    gemm_bt<4096, 6144, 2048, 1, true, true><<<dim3(48, 32), 256, 0, stream>>>(
        xb, wqb, bqkv, qb, kb, vb);
    attn_kernel<<<dim3(512), 512, 0, stream>>>(qb, kb, vb, ctx);
    gemm_bt<4096, 2048, 2048, 0, true, true><<<dim3(16, 32), 256, 0, stream>>>(
        ctx, wob, bout, out, nullptr, nullptr);
  } else {
    // fallback: 48 MiB ws, fused fp32->bf16 staging in GEMMs, ctx in d_out
    u16* qb = (u16*)d_ws;
    u16* kb = qb + XB_E;
    u16* vb = kb + XB_E;
    u16* ctx = (u16*)d_out;
    float* tmpo = (float*)d_ws;   // over dead qb/kb at out-proj time

    gemm_bt<4096, 6144, 2048, 1, false, false><<<dim3(48, 32), 256, 0, stream>>>(
        x, Wqkv, bqkv, qb, kb, vb);
    attn_kernel<<<dim3(512), 512, 0, stream>>>(qb, kb, vb, ctx);
    gemm_bt<4096, 2048, 2048, 0, true, false><<<dim3(16, 32), 256, 0, stream>>>(
        ctx, Wout, bout, tmpo, nullptr, nullptr);
    hipMemcpyAsync(out, tmpo, (size_t)out_size * sizeof(float),
                   hipMemcpyDeviceToDevice, stream);
  }
}